// Round 4
// baseline (531.892 us; speedup 1.0000x reference)
//
#include <hip/hip_runtime.h>
#include <math.h>

#define T_   4
#define B_   32
#define C_   512
#define N_   196
#define TB_  128
#define M_   25088          // TB_*N_
#define BNP_ 6272           // B_*N_  (t-plane stride in bn-space)
#define OUT1_ 12845056      // T_*B_*C_*N_

typedef unsigned short ushort_t;
typedef __attribute__((ext_vector_type(8)))  __bf16 bf16x8;
typedef __attribute__((ext_vector_type(16))) float  f32x16;

__device__ __forceinline__ ushort_t f2bf(float f) {
    unsigned int u = __float_as_uint(f);
    u = u + 0x7FFFu + ((u >> 16) & 1u);      // RN-even
    return (ushort_t)(u >> 16);
}
__device__ __forceinline__ float bf2f(ushort_t h) {
    return __uint_as_float(((unsigned int)h) << 16);
}

#define GL2LDS(gp, lp) \
    __builtin_amdgcn_global_load_lds((const __attribute__((address_space(1))) void*)(gp), \
                                     (__attribute__((address_space(3))) void*)(lp), 16, 0, 0)

// ---------------------------------------------------------------------------
// K0: prep — BN fold, 2-way bf16 weight split, bf16 out weights.
// ---------------------------------------------------------------------------
__global__ void prep_kernel(
    const float* __restrict__ qw, const float* __restrict__ kw,
    const float* __restrict__ vw, const float* __restrict__ ow,
    const float* __restrict__ qg, const float* __restrict__ qb, const float* __restrict__ qm, const float* __restrict__ qv,
    const float* __restrict__ kg, const float* __restrict__ kb, const float* __restrict__ km, const float* __restrict__ kvr,
    const float* __restrict__ vg, const float* __restrict__ vb, const float* __restrict__ vm, const float* __restrict__ vv,
    const float* __restrict__ og, const float* __restrict__ ob, const float* __restrict__ om, const float* __restrict__ ov,
    const float* __restrict__ obias,
    ushort_t* __restrict__ wsplit, ushort_t* __restrict__ osplit,
    float* __restrict__ scale_qkv, float* __restrict__ shift_qkv,
    float* __restrict__ scale_o,   float* __restrict__ shift_o,
    float* __restrict__ kvpart)
{
    int i = blockIdx.x * 256 + threadIdx.x;      // [0, 1536*512)
    int d = i >> 9, c = i & 511;
    const float* src = (d < 512) ? qw : (d < 1024) ? kw : vw;
    float wv = src[(d & 511) * 512 + c];
    ushort_t h = f2bf(wv);
    float r1 = wv - bf2f(h);
    ushort_t mm = f2bf(r1);
    wsplit[((size_t)d * 2 + 0) * 512 + c] = h;
    wsplit[((size_t)d * 2 + 1) * 512 + c] = mm;
    if (d < 512)
        osplit[(size_t)d * 512 + c] = f2bf(ow[d * 512 + c]);

    if (i < 3 * C_) {
        int p = i >> 9, dl = i & 511;
        const float* g = (p == 0) ? qg : (p == 1) ? kg : vg;
        const float* b = (p == 0) ? qb : (p == 1) ? kb : vb;
        const float* m = (p == 0) ? qm : (p == 1) ? km : vm;
        const float* r = (p == 0) ? qv : (p == 1) ? kvr : vv;
        float sc = g[dl] / sqrtf(r[dl] + 1e-5f);
        scale_qkv[i] = sc;
        shift_qkv[i] = b[dl] - m[dl] * sc;
    }
    if (i < C_) {
        float sc = og[i] / sqrtf(ov[i] + 1e-5f);
        scale_o[i] = sc;
        shift_o[i] = ob[i] - om[i] * sc + obias[i] * sc;
    }
    if (i < TB_ * C_) kvpart[i] = 0.f;
}

// ---------------------------------------------------------------------------
// K1: xs = lif(x), transposed to [m'][c] bf16 spikes, m' = (b*196+n)*4 + t
// ---------------------------------------------------------------------------
__global__ __launch_bounds__(256)
void lifx_kernel(const float* __restrict__ x, ushort_t* __restrict__ xs)
{
    __shared__ ushort_t tile[64 * 66];
    const int tid = threadIdx.x;
    const int b = blockIdx.z, c0 = blockIdx.y * 64, n0 = blockIdx.x * 64;
    const int j = tid & 63, w = tid >> 6;
    const bool nok = (n0 + j) < N_;
    float v[16];
#pragma unroll
    for (int r = 0; r < 16; ++r) v[r] = 0.f;
    for (int t = 0; t < T_; ++t) {
        const float* xb = x + ((size_t)((t * B_ + b) * C_ + c0)) * N_ + n0 + j;
#pragma unroll
        for (int r = 0; r < 16; ++r) {
            int i = w * 16 + r;
            float xv = nok ? xb[(size_t)i * N_] : 0.f;
            v[r] = v[r] + (xv - v[r]) * 0.5f;
            bool s = (v[r] >= 1.0f);
            tile[j * 66 + i] = s ? 0x3F80 : 0;
            if (s) v[r] = 0.f;
        }
        __syncthreads();
#pragma unroll
        for (int p = 0; p < 2; ++p) {
            int w2 = tid + p * 256;
            int jj = w2 >> 3, ck = w2 & 7;
            if (n0 + jj < N_) {
                const unsigned int* src = reinterpret_cast<const unsigned int*>(&tile[jj * 66 + ck * 8]);
                uint4 dv; dv.x = src[0]; dv.y = src[1]; dv.z = src[2]; dv.w = src[3];
                size_t mp = (size_t)(b * N_ + n0 + jj) * 4 + t;      // permuted row
                *reinterpret_cast<uint4*>(&xs[mp * 512 + c0 + ck * 8]) = dv;
            }
        }
        __syncthreads();
    }
}

// ---------------------------------------------------------------------------
// K2: qkv GEMM, 32x32x16 MFMA, 256x128 tile, 2-split weights,
// fused BN + LIF epilogue; v-plane also emits vh (out2, fp32).
// Round 4: LDS-FREE. Audit showed the old LDS staging was a per-lane
// identity copy (GL2LDS writes lane L at chunk+L*16; fragment reads at
// lane*16 read the same bytes back) — so each wave now loads its MFMA
// fragments DIRECTLY global->VGPR. No LDS, no barriers, no lockstep:
// every wave free-runs, latency hidden by 4 waves/SIMD + vmcnt pipelining.
// Intra-block fragment sharing (X x2, W x4) now served by L1/L2 (W 3.1MB +
// per-XCD X slab are L2-resident via the XCD swizzle). Addresses: 32-bit
// voffsets from uniform base (saddr form), K-walk in the 13-bit imm.
// W loads grouped per-split s to keep live frags ~116 VGPR (< 128 cliff).
// ---------------------------------------------------------------------------
__global__ __launch_bounds__(512, 4)
void qkv_gemm_lif(const ushort_t* __restrict__ W, const ushort_t* __restrict__ X,
                  const float* __restrict__ scale, const float* __restrict__ shift,
                  ushort_t* __restrict__ spk, float* __restrict__ out2)
{
    const int id = blockIdx.x;
    const int xw = id & 7, local = id >> 3;      // local in [0,150)
    const int ml = local / 12, d_t = local - ml * 12;
    const int m_t = ml * 8 + xw;
    if (m_t >= 98) return;
    const int m0 = m_t * 256;                    // m' base (256-tile)
    const int d0 = d_t * 128;                    // global d in [0,1536)

    const int tid = threadIdx.x, wid = tid >> 6, lane = tid & 63;
    const int mw = (wid & 3) * 64, dw = (wid >> 2) * 64;
    const int row32 = lane & 31, khalf = lane >> 5;

    // 32-bit per-lane fragment offsets (ushort units), k0 added per iter
    unsigned xo[2][2];        // [i][ks]
    unsigned wo[2][2][2];     // [s][j][ks]
#pragma unroll
    for (int i = 0; i < 2; ++i)
#pragma unroll
        for (int ks = 0; ks < 2; ++ks)
            xo[i][ks] = (unsigned)((m0 + mw + i * 32 + row32) * 512 + ks * 16 + khalf * 8);
#pragma unroll
    for (int s = 0; s < 2; ++s)
#pragma unroll
        for (int j = 0; j < 2; ++j)
#pragma unroll
            for (int ks = 0; ks < 2; ++ks)
                wo[s][j][ks] = (unsigned)(((d0 + dw + j * 32 + row32) * 2 + s) * 512 + ks * 16 + khalf * 8);

    f32x16 acc[2][2] = {};               // [i: m-block32][j: d-block32]

    for (int k0 = 0; k0 < 512; k0 += 32) {
        bf16x8 xfr[2][2];
#pragma unroll
        for (int i = 0; i < 2; ++i)
#pragma unroll
            for (int ks = 0; ks < 2; ++ks)
                xfr[i][ks] = *reinterpret_cast<const bf16x8*>(X + xo[i][ks] + k0);
#pragma unroll
        for (int s = 0; s < 2; ++s) {
            bf16x8 wfr[2][2];
#pragma unroll
            for (int j = 0; j < 2; ++j)
#pragma unroll
                for (int ks = 0; ks < 2; ++ks)
                    wfr[j][ks] = *reinterpret_cast<const bf16x8*>(W + wo[s][j][ks] + k0);
#pragma unroll
            for (int ks = 0; ks < 2; ++ks)
#pragma unroll
                for (int j = 0; j < 2; ++j)
#pragma unroll
                    for (int i = 0; i < 2; ++i)
                        acc[i][j] = __builtin_amdgcn_mfma_f32_32x32x16_bf16(xfr[i][ks], wfr[j][ks], acc[i][j], 0, 0, 0);
        }
    }

    // epilogue: BN -> LIF over t (reg&3) -> bf16 spike planes [t][bn][c];
    // v-plane additionally writes out2[t][b][h][n][hd] fp32
    const int p = d0 >> 9;
    const bool isV = (p == 2);
    ushort_t* plane = spk + (size_t)p * ((size_t)M_ * 512);
#pragma unroll
    for (int j = 0; j < 2; ++j) {
        int d = d0 + dw + j * 32 + row32;
        float sc = scale[d], sh = shift[d];
        int dl = d & 511;
        int h = dl >> 6, hd = dl & 63;
#pragma unroll
        for (int i = 0; i < 2; ++i) {
            int bnb = (m0 + mw + i * 32) >> 2;
            f32x16 a = acc[i][j];
#pragma unroll
            for (int g = 0; g < 4; ++g) {
                int bn = bnb + 2 * g + khalf;
                float p0 = fmaf(a[4 * g + 0], sc, sh);
                float p1 = fmaf(a[4 * g + 1], sc, sh);
                float p2 = fmaf(a[4 * g + 2], sc, sh);
                float p3 = fmaf(a[4 * g + 3], sc, sh);
                float v = p0 * 0.5f;
                bool s0 = (v >= 1.f); if (s0) v = 0.f;
                v = v + (p1 - v) * 0.5f;
                bool s1 = (v >= 1.f); if (s1) v = 0.f;
                v = v + (p2 - v) * 0.5f;
                bool s2 = (v >= 1.f); if (s2) v = 0.f;
                v = v + (p3 - v) * 0.5f;
                bool s3 = (v >= 1.f);
                ushort_t* b0 = plane + (size_t)bn * 512 + dl;
                b0[0]                      = s0 ? 0x3F80 : 0;
                b0[(size_t)BNP_ * 512]     = s1 ? 0x3F80 : 0;
                b0[(size_t)2 * BNP_ * 512] = s2 ? 0x3F80 : 0;
                b0[(size_t)3 * BNP_ * 512] = s3 ? 0x3F80 : 0;
                if (isV) {
                    int b = bn / N_, n = bn - b * N_;
                    float* o = out2 + (((size_t)b * 8 + h) * N_ + n) * 64 + hd;
                    o[0]                       = s0 ? 1.f : 0.f;
                    o[(size_t)1 * (OUT1_ / 4)] = s1 ? 1.f : 0.f;
                    o[(size_t)2 * (OUT1_ / 4)] = s2 ? 1.f : 0.f;
                    o[(size_t)3 * (OUT1_ / 4)] = s3 ? 1.f : 0.f;
                }
            }
        }
    }
}

// ---------------------------------------------------------------------------
// K3: kvpart[tb][c] = sum_n (k_s & v_s)  — uint4 loads, LDS-count, no
// global atomics, direct store. grid 256: id -> tb(128) x ch(2).
// thread: cg = tid&31 (8-channel group), ns = tid>>5 (n-chunk of 25).
// ---------------------------------------------------------------------------
__global__ __launch_bounds__(256)
void kv_part_kernel(const ushort_t* __restrict__ ks, const ushort_t* __restrict__ vs,
                    float* __restrict__ kvpart)
{
    __shared__ int cnt[256];
    const int tid = threadIdx.x;
    cnt[tid] = 0;
    __syncthreads();
    const int tb = blockIdx.x >> 1, ch = blockIdx.x & 1;
    const int cg = tid & 31, ns = tid >> 5;
    const int c = ch * 256 + cg * 8;
    const ushort_t* kb = ks + (size_t)tb * N_ * 512 + c;
    const ushort_t* vb = vs + (size_t)tb * N_ * 512 + c;
    int loc[8] = {0, 0, 0, 0, 0, 0, 0, 0};
    int n1 = ns * 25 + 25; if (n1 > N_) n1 = N_;
    for (int n = ns * 25; n < n1; ++n) {
        uint4 kq = *reinterpret_cast<const uint4*>(&kb[(size_t)n * 512]);
        uint4 vq = *reinterpret_cast<const uint4*>(&vb[(size_t)n * 512]);
        unsigned m;
        m = kq.x & vq.x; loc[0] += (m & 0xFFFFu) ? 1 : 0; loc[1] += (m >> 16) ? 1 : 0;
        m = kq.y & vq.y; loc[2] += (m & 0xFFFFu) ? 1 : 0; loc[3] += (m >> 16) ? 1 : 0;
        m = kq.z & vq.z; loc[4] += (m & 0xFFFFu) ? 1 : 0; loc[5] += (m >> 16) ? 1 : 0;
        m = kq.w & vq.w; loc[6] += (m & 0xFFFFu) ? 1 : 0; loc[7] += (m >> 16) ? 1 : 0;
    }
#pragma unroll
    for (int e = 0; e < 8; ++e) atomicAdd(&cnt[cg * 8 + e], loc[e]);
    __syncthreads();
    kvpart[tb * 512 + ch * 256 + tid] = (float)cnt[tid];
}

// ---------------------------------------------------------------------------
// K4: LIF over t on kvpart -> kv spikes bf16 [tb][c]
// ---------------------------------------------------------------------------
__global__ void kv_lif_kernel(const float* __restrict__ kvpart, ushort_t* __restrict__ kvs)
{
    int i = blockIdx.x * 256 + threadIdx.x;      // 32*512
    if (i >= B_ * C_) return;
    int b = i >> 9, c = i & 511;
    float v = 0.f;
#pragma unroll
    for (int t = 0; t < T_; ++t) {
        float y = kvpart[((t * B_ + b) << 9) + c];
        v = v + (y - v) * 0.5f;
        bool s = (v >= 1.f);
        kvs[((t * B_ + b) << 9) + c] = s ? 0x3F80 : 0;
        if (s) v = 0.f;
    }
}

// ---------------------------------------------------------------------------
// K6: out GEMM with fused muly: B-tile staged as (q_s & kvs) via VALU+ds_write.
// Double-buffered 1-barrier/K-step pipeline: issue B reg-loads + A GL2LDS for
// t+1 BEFORE the MFMA phase (latency hides under compute), AND+ds_write
// after, single __syncthreads drain. Epilogue: BN+bias+identity.
// ---------------------------------------------------------------------------
__global__ __launch_bounds__(256)
void out_gemm(const ushort_t* __restrict__ A, const ushort_t* __restrict__ qs,
              const ushort_t* __restrict__ kvs,
              const float* __restrict__ scale, const float* __restrict__ shift,
              const float* __restrict__ xid, float* __restrict__ out)
{
    const int id = blockIdx.x;
    const int xw = id & 7, local = id >> 3;      // local < 100
    const int m_t = (local >> 2) * 8 + xw, d_t = local & 3;
    if (m_t >= 196) return;
    const int m0 = m_t * 128, d0 = d_t * 128;

    __shared__ ushort_t As[2][8 * 512];  // dbuf x [db(4)][ks(2)]
    __shared__ ushort_t Bs[2][8 * 512];  // dbuf x [mb(4)][ks(2)]
    const int tid = threadIdx.x, wid = tid >> 6, lane = tid & 63;
    const int dw = (wid >> 1) * 64, mw = (wid & 1) * 64;
    const int row32 = lane & 31, khalf = lane >> 5;

    // per-thread B-staging slots (constant across K-loop)
    int sm[2], stb[2], sq[2], sL[2];
#pragma unroll
    for (int u = 0; u < 2; ++u) {
        int s = tid + u * 256;
        sq[u] = s >> 6; sL[u] = s & 63;
        sm[u] = m0 + (sq[u] >> 1) * 32 + (sL[u] & 31);
        stb[u] = sm[u] / N_;
    }

    f32x16 acc[2][2] = {};               // [i: d-block32][j: m-block32]

    // prologue: stage tile 0 into buf 0
    {
        uint4 o[2];
#pragma unroll
        for (int u = 0; u < 2; ++u) {
            int kk = (sq[u] & 1) * 16 + (sL[u] >> 5) * 8;
            uint4 qv = *reinterpret_cast<const uint4*>(&qs[(size_t)sm[u] * 512 + kk]);
            uint4 kv = *reinterpret_cast<const uint4*>(&kvs[(size_t)stb[u] * 512 + kk]);
            o[u].x = qv.x & kv.x; o[u].y = qv.y & kv.y;
            o[u].z = qv.z & kv.z; o[u].w = qv.w & kv.w;
        }
        for (int q = wid; q < 8; q += 4) {
            int db = q >> 1, ks2 = q & 1;
            const ushort_t* g = A + (size_t)(d0 + db * 32 + row32) * 512 + ks2 * 16 + khalf * 8;
            GL2LDS(g, &As[0][q * 512]);
        }
#pragma unroll
        for (int u = 0; u < 2; ++u)
            *reinterpret_cast<uint4*>(&Bs[0][sq[u] * 512 + sL[u] * 8]) = o[u];
    }
    __syncthreads();

    int buf = 0;
    for (int it = 0; it < 16; ++it) {
        uint4 nq[2], nk[2];
        if (it < 15) {
            int k0n = (it + 1) * 32;
#pragma unroll
            for (int u = 0; u < 2; ++u) {
                int kk = k0n + (sq[u] & 1) * 16 + (sL[u] >> 5) * 8;
                nq[u] = *reinterpret_cast<const uint4*>(&qs[(size_t)sm[u] * 512 + kk]);
                nk[u] = *reinterpret_cast<const uint4*>(&kvs[(size_t)stb[u] * 512 + kk]);
            }
            for (int q = wid; q < 8; q += 4) {
                int db = q >> 1, ks2 = q & 1;
                const ushort_t* g = A + (size_t)(d0 + db * 32 + row32) * 512 + k0n + ks2 * 16 + khalf * 8;
                GL2LDS(g, &As[buf ^ 1][q * 512]);
            }
        }

        __builtin_amdgcn_s_setprio(1);
#pragma unroll
        for (int ks = 0; ks < 2; ++ks) {
            bf16x8 afr[2];
#pragma unroll
            for (int i = 0; i < 2; ++i)
                afr[i] = *reinterpret_cast<const bf16x8*>(
                    &As[buf][(((dw >> 5) + i) * 2 + ks) * 512 + lane * 8]);
#pragma unroll
            for (int j = 0; j < 2; ++j) {
                bf16x8 bfr = *reinterpret_cast<const bf16x8*>(
                    &Bs[buf][(((mw >> 5) + j) * 2 + ks) * 512 + lane * 8]);
#pragma unroll
                for (int i = 0; i < 2; ++i)
                    acc[i][j] = __builtin_amdgcn_mfma_f32_32x32x16_bf16(afr[i], bfr, acc[i][j], 0, 0, 0);
            }
        }
        __builtin_amdgcn_s_setprio(0);

        if (it < 15) {
#pragma unroll
            for (int u = 0; u < 2; ++u) {
                uint4 o;
                o.x = nq[u].x & nk[u].x; o.y = nq[u].y & nk[u].y;
                o.z = nq[u].z & nk[u].z; o.w = nq[u].w & nk[u].w;
                *reinterpret_cast<uint4*>(&Bs[buf ^ 1][sq[u] * 512 + sL[u] * 8]) = o;
            }
        }
        __syncthreads();      // drains vmcnt(0): A(t+1) landed; lgkm: Bs visible
        buf ^= 1;
    }

#pragma unroll
    for (int j = 0; j < 2; ++j) {
        int m = m0 + mw + j * 32 + row32;     // n contiguous across lanes
        int tb = m / N_;
        int n  = m - tb * N_;
        size_t mbase = (size_t)tb * (C_ * N_) + n;
#pragma unroll
        for (int i = 0; i < 2; ++i) {
            int dbase = d0 + dw + i * 32 + 4 * khalf;
            f32x16 a = acc[i][j];
#pragma unroll
            for (int g = 0; g < 4; ++g) {
#pragma unroll
                for (int t = 0; t < 4; ++t) {
                    int d = dbase + t + 8 * g;
                    float val = fmaf(a[4 * g + t], scale[d], shift[d]);
                    size_t ad = mbase + (size_t)d * N_;
                    out[ad] = val + xid[ad];
                }
            }
        }
    }
}

// ---------------------------------------------------------------------------
extern "C" void kernel_launch(void* const* d_in, const int* in_sizes, int n_in,
                              void* d_out, int out_size, void* d_ws, size_t ws_size,
                              hipStream_t stream)
{
    const float* x    = (const float*)d_in[0];
    const float* q_w  = (const float*)d_in[1];
    const float* k_w  = (const float*)d_in[2];
    const float* v_w  = (const float*)d_in[3];
    const float* o_w  = (const float*)d_in[4];
    const float* o_b  = (const float*)d_in[5];
    const float* qg = (const float*)d_in[6],  *qb = (const float*)d_in[7],
               *qm = (const float*)d_in[8],  *qv = (const float*)d_in[9];
    const float* kg = (const float*)d_in[10], *kb = (const float*)d_in[11],
               *km = (const float*)d_in[12], *kv = (const float*)d_in[13];
    const float* vg = (const float*)d_in[14], *vb = (const float*)d_in[15],
               *vm = (const float*)d_in[16], *vv = (const float*)d_in[17];
    const float* og = (const float*)d_in[18], *ob = (const float*)d_in[19],
               *om = (const float*)d_in[20], *ov = (const float*)d_in[21];

    float* out1  = (float*)d_out;
    float* out2f = out1 + OUT1_;

    // d_ws layout
    ushort_t* spk    = (ushort_t*)d_ws;                      // [3][M][512] bf16 spikes
    ushort_t* xs     = spk + (size_t)3 * M_ * 512;           // [M][512] bf16 (m' order)
    ushort_t* wsplit = xs + (size_t)M_ * 512;                // 1536*2*512
    ushort_t* osplit = wsplit + (size_t)1536 * 2 * 512;      // 512*512
    float*    kvpart = (float*)(osplit + (size_t)512 * 512); // [TB][C]
    ushort_t* kvs    = (ushort_t*)(kvpart + TB_ * C_);       // [TB][C]
    float*    scq    = (float*)(kvs + TB_ * C_);
    float*    shq    = scq + 3 * C_;
    float*    sco    = shq + 3 * C_;
    float*    sho    = sco + C_;

    ushort_t* qsp = spk;
    ushort_t* ksp = spk + (size_t)M_ * 512;
    ushort_t* vsp = spk + (size_t)2 * M_ * 512;

    prep_kernel<<<(1536 * 512) / 256, 256, 0, stream>>>(
        q_w, k_w, v_w, o_w,
        qg, qb, qm, qv, kg, kb, km, kv, vg, vb, vm, vv, og, ob, om, ov, o_b,
        wsplit, osplit, scq, shq, sco, sho, kvpart);

    lifx_kernel<<<dim3(4, 8, 32), 256, 0, stream>>>(x, xs);

    qkv_gemm_lif<<<1200, 512, 0, stream>>>(wsplit, xs, scq, shq, spk, out2f);

    kv_part_kernel<<<256, 256, 0, stream>>>(ksp, vsp, kvpart);

    kv_lif_kernel<<<64, 256, 0, stream>>>(kvpart, kvs);

    out_gemm<<<800, 256, 0, stream>>>(osplit, qsp, kvs, sco, sho, x, out1);
}

// Round 7
// 404.015 us; speedup vs baseline: 1.3165x; 1.3165x over previous
//
#include <hip/hip_runtime.h>
#include <math.h>

#define T_   4
#define B_   32
#define C_   512
#define N_   196
#define TB_  128
#define M_   25088          // TB_*N_
#define BNP_ 6272           // B_*N_  (t-plane stride in bn-space)
#define OUT1_ 12845056      // T_*B_*C_*N_

typedef unsigned short ushort_t;
typedef __attribute__((ext_vector_type(8)))  __bf16 bf16x8;
typedef __attribute__((ext_vector_type(16))) float  f32x16;

__device__ __forceinline__ ushort_t f2bf(float f) {
    unsigned int u = __float_as_uint(f);
    u = u + 0x7FFFu + ((u >> 16) & 1u);      // RN-even
    return (ushort_t)(u >> 16);
}
__device__ __forceinline__ float bf2f(ushort_t h) {
    return __uint_as_float(((unsigned int)h) << 16);
}

#define GL2LDS(gp, lp) \
    __builtin_amdgcn_global_load_lds((const __attribute__((address_space(1))) void*)(gp), \
                                     (__attribute__((address_space(3))) void*)(lp), 16, 0, 0)

// ---------------------------------------------------------------------------
// K0+K1 merged: blocks [0,3072) = prep (BN fold, 2-way bf16 weight split,
// bf16 out weights); blocks [3072,4096) = lifx (xs = lif(x) transposed to
// [m'][c] bf16 spikes, m' = (b*196+n)*4 + t). Pure blockIdx remap of the
// two previously-passing kernels; saves one launch gap. qkv depends on both
// outputs, so the merged kernel completing before qkv preserves all deps.
// ---------------------------------------------------------------------------
__global__ __launch_bounds__(256)
void prep_lifx_kernel(
    const float* __restrict__ qw, const float* __restrict__ kw,
    const float* __restrict__ vw, const float* __restrict__ ow,
    const float* __restrict__ qg, const float* __restrict__ qb, const float* __restrict__ qm, const float* __restrict__ qv,
    const float* __restrict__ kg, const float* __restrict__ kb, const float* __restrict__ km, const float* __restrict__ kvr,
    const float* __restrict__ vg, const float* __restrict__ vb, const float* __restrict__ vm, const float* __restrict__ vv,
    const float* __restrict__ og, const float* __restrict__ ob, const float* __restrict__ om, const float* __restrict__ ov,
    const float* __restrict__ obias,
    ushort_t* __restrict__ wsplit, ushort_t* __restrict__ osplit,
    float* __restrict__ scale_qkv, float* __restrict__ shift_qkv,
    float* __restrict__ scale_o,   float* __restrict__ shift_o,
    float* __restrict__ kvpart,
    const float* __restrict__ x, ushort_t* __restrict__ xs)
{
    __shared__ ushort_t tile[64 * 66];
    const int bid = blockIdx.x;
    const int tid = threadIdx.x;

    if (bid < 3072) {
        // ----- prep region -----
        int i = bid * 256 + tid;                 // [0, 1536*512)
        int d = i >> 9, c = i & 511;
        const float* src = (d < 512) ? qw : (d < 1024) ? kw : vw;
        float wv = src[(d & 511) * 512 + c];
        ushort_t h = f2bf(wv);
        float r1 = wv - bf2f(h);
        ushort_t mm = f2bf(r1);
        wsplit[((size_t)d * 2 + 0) * 512 + c] = h;
        wsplit[((size_t)d * 2 + 1) * 512 + c] = mm;
        if (d < 512)
            osplit[(size_t)d * 512 + c] = f2bf(ow[d * 512 + c]);

        if (i < 3 * C_) {
            int p = i >> 9, dl = i & 511;
            const float* g = (p == 0) ? qg : (p == 1) ? kg : vg;
            const float* b = (p == 0) ? qb : (p == 1) ? kb : vb;
            const float* m = (p == 0) ? qm : (p == 1) ? km : vm;
            const float* r = (p == 0) ? qv : (p == 1) ? kvr : vv;
            float sc = g[dl] / sqrtf(r[dl] + 1e-5f);
            scale_qkv[i] = sc;
            shift_qkv[i] = b[dl] - m[dl] * sc;
        }
        if (i < C_) {
            float sc = og[i] / sqrtf(ov[i] + 1e-5f);
            scale_o[i] = sc;
            shift_o[i] = ob[i] - om[i] * sc + obias[i] * sc;
        }
        if (i < TB_ * C_) kvpart[i] = 0.f;
        return;
    }

    // ----- lifx region -----
    const int l = bid - 3072;                    // [0, 1024)
    const int n0 = (l & 3) * 64;
    const int c0 = ((l >> 2) & 7) * 64;
    const int b  = l >> 5;
    const int j = tid & 63, w = tid >> 6;
    const bool nok = (n0 + j) < N_;
    float v[16];
#pragma unroll
    for (int r = 0; r < 16; ++r) v[r] = 0.f;
    for (int t = 0; t < T_; ++t) {
        const float* xb = x + ((size_t)((t * B_ + b) * C_ + c0)) * N_ + n0 + j;
#pragma unroll
        for (int r = 0; r < 16; ++r) {
            int i = w * 16 + r;
            float xv = nok ? xb[(size_t)i * N_] : 0.f;
            v[r] = v[r] + (xv - v[r]) * 0.5f;
            bool s = (v[r] >= 1.0f);
            tile[j * 66 + i] = s ? 0x3F80 : 0;
            if (s) v[r] = 0.f;
        }
        __syncthreads();
#pragma unroll
        for (int p = 0; p < 2; ++p) {
            int w2 = tid + p * 256;
            int jj = w2 >> 3, ck = w2 & 7;
            if (n0 + jj < N_) {
                const unsigned int* src = reinterpret_cast<const unsigned int*>(&tile[jj * 66 + ck * 8]);
                uint4 dv; dv.x = src[0]; dv.y = src[1]; dv.z = src[2]; dv.w = src[3];
                size_t mp = (size_t)(b * N_ + n0 + jj) * 4 + t;      // permuted row
                *reinterpret_cast<uint4*>(&xs[mp * 512 + c0 + ck * 8]) = dv;
            }
        }
        __syncthreads();
    }
}

// ---------------------------------------------------------------------------
// K2: qkv GEMM, 32x32x16 MFMA, 256x128 tile, 2-split weights,
// fused BN + LIF epilogue; v-plane also emits vh (out2, fp32).
// Round-1 structure (best measured: 112 µs): 2-phase double-buffered
// pipeline — STAGE(next buf) issued BEFORE compute(cur buf); ONE
// __syncthreads per K-step. 512 threads / 8 waves, per-wave 64x64 ->
// acc[2][2] = 64 AGPRs, 16 waves/CU (2 blocks x 8 waves; 64KB LDS dbuf).
// XCD swizzle: xcd = id%8; per XCD m-major so the 2-split W (3.1 MB) stays
// L2-resident while the XCD's X slab streams.
// ---------------------------------------------------------------------------
__global__ __launch_bounds__(512, 4)
void qkv_gemm_lif(const ushort_t* __restrict__ W, const ushort_t* __restrict__ X,
                  const float* __restrict__ scale, const float* __restrict__ shift,
                  ushort_t* __restrict__ spk, float* __restrict__ out2)
{
    const int id = blockIdx.x;
    const int xw = id & 7, local = id >> 3;      // local in [0,150)
    const int ml = local / 12, d_t = local - ml * 12;
    const int m_t = ml * 8 + xw;
    if (m_t >= 98) return;
    const int m0 = m_t * 256;                    // m' base (256-tile)
    const int d0 = d_t * 128;                    // global d in [0,1536)

    __shared__ ushort_t Xs[2][16 * 512];  // dbuf x 16 chunks of 1KB: [mb(8)][ks(2)]
    __shared__ ushort_t Ws[2][16 * 512];  // dbuf x 16 chunks: [s(2)][db(4)][ks(2)]
    const int tid = threadIdx.x, wid = tid >> 6, lane = tid & 63;
    const int mw = (wid & 3) * 64, dw = (wid >> 2) * 64;
    const int row32 = lane & 31, khalf = lane >> 5;

    f32x16 acc[2][2] = {};               // [i: m-block32][j: d-block32]

    // stage one K-tile (k0) into buffer buf: each of 8 waves issues
    // 2 Xs chunks + 2 Ws chunks (wave-uniform LDS base, per-lane global src)
    auto STAGE = [&](int buf, int k0) {
        {   // Xs chunk q = wid
            int q = wid, mb = q >> 1, ks = q & 1;
            const ushort_t* g = X + (size_t)(m0 + mb * 32 + row32) * 512 + k0 + ks * 16 + khalf * 8;
            GL2LDS(g, &Xs[buf][q * 512]);
        }
        {   // Xs chunk q = wid+8
            int q = wid + 8, mb = q >> 1, ks = q & 1;
            const ushort_t* g = X + (size_t)(m0 + mb * 32 + row32) * 512 + k0 + ks * 16 + khalf * 8;
            GL2LDS(g, &Xs[buf][q * 512]);
        }
        {   // Ws chunk q = wid (split s=0)
            int q = wid, s = q >> 3, rem = q & 7, db = rem >> 1, ks = rem & 1;
            const ushort_t* g = W + ((size_t)(d0 + db * 32 + row32) * 2 + s) * 512 + k0 + ks * 16 + khalf * 8;
            GL2LDS(g, &Ws[buf][q * 512]);
        }
        {   // Ws chunk q = wid+8 (split s=1)
            int q = wid + 8, s = q >> 3, rem = q & 7, db = rem >> 1, ks = rem & 1;
            const ushort_t* g = W + ((size_t)(d0 + db * 32 + row32) * 2 + s) * 512 + k0 + ks * 16 + khalf * 8;
            GL2LDS(g, &Ws[buf][q * 512]);
        }
    };

    // prologue
    STAGE(0, 0);
    __syncthreads();                      // drains vmcnt(0) -> buf0 ready
    int cur = 0;

    for (int it = 0; it < 16; ++it) {
        if (it < 15) STAGE(cur ^ 1, (it + 1) * 32);   // issue next tile FIRST

        __builtin_amdgcn_s_setprio(1);
#pragma unroll
        for (int ks = 0; ks < 2; ++ks) {
            bf16x8 xfr[2];
#pragma unroll
            for (int i = 0; i < 2; ++i)
                xfr[i] = *reinterpret_cast<const bf16x8*>(
                    &Xs[cur][(((mw >> 5) + i) * 2 + ks) * 512 + lane * 8]);
#pragma unroll
            for (int s = 0; s < 2; ++s)
#pragma unroll
                for (int j = 0; j < 2; ++j) {
                    bf16x8 wfr = *reinterpret_cast<const bf16x8*>(
                        &Ws[cur][(s * 8 + ((dw >> 5) + j) * 2 + ks) * 512 + lane * 8]);
#pragma unroll
                    for (int i = 0; i < 2; ++i)
                        acc[i][j] = __builtin_amdgcn_mfma_f32_32x32x16_bf16(xfr[i], wfr, acc[i][j], 0, 0, 0);
                }
        }
        __builtin_amdgcn_s_setprio(0);

        // one barrier per K-step: ensures (a) my next-tile loads landed
        // (compiler drains vmcnt before s_barrier), (b) all waves done
        // reading buf[cur] before it is overwritten next iteration.
        __syncthreads();
        cur ^= 1;
    }

    // epilogue: BN -> LIF over t (reg&3) -> bf16 spike planes [t][bn][c];
    // v-plane additionally writes out2[t][b][h][n][hd] fp32
    const int p = d0 >> 9;
    const bool isV = (p == 2);
    ushort_t* plane = spk + (size_t)p * ((size_t)M_ * 512);
#pragma unroll
    for (int j = 0; j < 2; ++j) {
        int d = d0 + dw + j * 32 + row32;
        float sc = scale[d], sh = shift[d];
        int dl = d & 511;
        int h = dl >> 6, hd = dl & 63;
#pragma unroll
        for (int i = 0; i < 2; ++i) {
            int bnb = (m0 + mw + i * 32) >> 2;
            f32x16 a = acc[i][j];
#pragma unroll
            for (int g = 0; g < 4; ++g) {
                int bn = bnb + 2 * g + khalf;
                float p0 = fmaf(a[4 * g + 0], sc, sh);
                float p1 = fmaf(a[4 * g + 1], sc, sh);
                float p2 = fmaf(a[4 * g + 2], sc, sh);
                float p3 = fmaf(a[4 * g + 3], sc, sh);
                float v = p0 * 0.5f;
                bool s0 = (v >= 1.f); if (s0) v = 0.f;
                v = v + (p1 - v) * 0.5f;
                bool s1 = (v >= 1.f); if (s1) v = 0.f;
                v = v + (p2 - v) * 0.5f;
                bool s2 = (v >= 1.f); if (s2) v = 0.f;
                v = v + (p3 - v) * 0.5f;
                bool s3 = (v >= 1.f);
                ushort_t* b0 = plane + (size_t)bn * 512 + dl;
                b0[0]                      = s0 ? 0x3F80 : 0;
                b0[(size_t)BNP_ * 512]     = s1 ? 0x3F80 : 0;
                b0[(size_t)2 * BNP_ * 512] = s2 ? 0x3F80 : 0;
                b0[(size_t)3 * BNP_ * 512] = s3 ? 0x3F80 : 0;
                if (isV) {
                    int b = bn / N_, n = bn - b * N_;
                    float* o = out2 + (((size_t)b * 8 + h) * N_ + n) * 64 + hd;
                    o[0]                       = s0 ? 1.f : 0.f;
                    o[(size_t)1 * (OUT1_ / 4)] = s1 ? 1.f : 0.f;
                    o[(size_t)2 * (OUT1_ / 4)] = s2 ? 1.f : 0.f;
                    o[(size_t)3 * (OUT1_ / 4)] = s3 ? 1.f : 0.f;
                }
            }
        }
    }
}

// ---------------------------------------------------------------------------
// K3: kvpart[tb][c] = sum_n (k_s & v_s)  — uint4 loads, LDS-count, no
// global atomics, direct store. grid 256: id -> tb(128) x ch(2).
// ---------------------------------------------------------------------------
__global__ __launch_bounds__(256)
void kv_part_kernel(const ushort_t* __restrict__ ks, const ushort_t* __restrict__ vs,
                    float* __restrict__ kvpart)
{
    __shared__ int cnt[256];
    const int tid = threadIdx.x;
    cnt[tid] = 0;
    __syncthreads();
    const int tb = blockIdx.x >> 1, ch = blockIdx.x & 1;
    const int cg = tid & 31, ns = tid >> 5;
    const int c = ch * 256 + cg * 8;
    const ushort_t* kb = ks + (size_t)tb * N_ * 512 + c;
    const ushort_t* vb = vs + (size_t)tb * N_ * 512 + c;
    int loc[8] = {0, 0, 0, 0, 0, 0, 0, 0};
    int n1 = ns * 25 + 25; if (n1 > N_) n1 = N_;
    for (int n = ns * 25; n < n1; ++n) {
        uint4 kq = *reinterpret_cast<const uint4*>(&kb[(size_t)n * 512]);
        uint4 vq = *reinterpret_cast<const uint4*>(&vb[(size_t)n * 512]);
        unsigned m;
        m = kq.x & vq.x; loc[0] += (m & 0xFFFFu) ? 1 : 0; loc[1] += (m >> 16) ? 1 : 0;
        m = kq.y & vq.y; loc[2] += (m & 0xFFFFu) ? 1 : 0; loc[3] += (m >> 16) ? 1 : 0;
        m = kq.z & vq.z; loc[4] += (m & 0xFFFFu) ? 1 : 0; loc[5] += (m >> 16) ? 1 : 0;
        m = kq.w & vq.w; loc[6] += (m & 0xFFFFu) ? 1 : 0; loc[7] += (m >> 16) ? 1 : 0;
    }
#pragma unroll
    for (int e = 0; e < 8; ++e) atomicAdd(&cnt[cg * 8 + e], loc[e]);
    __syncthreads();
    kvpart[tb * 512 + ch * 256 + tid] = (float)cnt[tid];
}

// ---------------------------------------------------------------------------
// K4: LIF over t on kvpart -> kv spikes bf16 [tb][c]
// ---------------------------------------------------------------------------
__global__ void kv_lif_kernel(const float* __restrict__ kvpart, ushort_t* __restrict__ kvs)
{
    int i = blockIdx.x * 256 + threadIdx.x;      // 32*512
    if (i >= B_ * C_) return;
    int b = i >> 9, c = i & 511;
    float v = 0.f;
#pragma unroll
    for (int t = 0; t < T_; ++t) {
        float y = kvpart[((t * B_ + b) << 9) + c];
        v = v + (y - v) * 0.5f;
        bool s = (v >= 1.f);
        kvs[((t * B_ + b) << 9) + c] = s ? 0x3F80 : 0;
        if (s) v = 0.f;
    }
}

// ---------------------------------------------------------------------------
// K6: out GEMM with fused muly: B-tile staged as (q_s & kvs) via VALU+ds_write.
// Double-buffered 1-barrier/K-step pipeline: issue B reg-loads + A GL2LDS for
// t+1 BEFORE the MFMA phase (latency hides under compute), AND+ds_write
// after, single __syncthreads drain. Epilogue: BN+bias+identity.
// ---------------------------------------------------------------------------
__global__ __launch_bounds__(256)
void out_gemm(const ushort_t* __restrict__ A, const ushort_t* __restrict__ qs,
              const ushort_t* __restrict__ kvs,
              const float* __restrict__ scale, const float* __restrict__ shift,
              const float* __restrict__ xid, float* __restrict__ out)
{
    const int id = blockIdx.x;
    const int xw = id & 7, local = id >> 3;      // local < 100
    const int m_t = (local >> 2) * 8 + xw, d_t = local & 3;
    if (m_t >= 196) return;
    const int m0 = m_t * 128, d0 = d_t * 128;

    __shared__ ushort_t As[2][8 * 512];  // dbuf x [db(4)][ks(2)]
    __shared__ ushort_t Bs[2][8 * 512];  // dbuf x [mb(4)][ks(2)]
    const int tid = threadIdx.x, wid = tid >> 6, lane = tid & 63;
    const int dw = (wid >> 1) * 64, mw = (wid & 1) * 64;
    const int row32 = lane & 31, khalf = lane >> 5;

    // per-thread B-staging slots (constant across K-loop)
    int sm[2], stb[2], sq[2], sL[2];
#pragma unroll
    for (int u = 0; u < 2; ++u) {
        int s = tid + u * 256;
        sq[u] = s >> 6; sL[u] = s & 63;
        sm[u] = m0 + (sq[u] >> 1) * 32 + (sL[u] & 31);
        stb[u] = sm[u] / N_;
    }

    f32x16 acc[2][2] = {};               // [i: d-block32][j: m-block32]

    // prologue: stage tile 0 into buf 0
    {
        uint4 o[2];
#pragma unroll
        for (int u = 0; u < 2; ++u) {
            int kk = (sq[u] & 1) * 16 + (sL[u] >> 5) * 8;
            uint4 qv = *reinterpret_cast<const uint4*>(&qs[(size_t)sm[u] * 512 + kk]);
            uint4 kv = *reinterpret_cast<const uint4*>(&kvs[(size_t)stb[u] * 512 + kk]);
            o[u].x = qv.x & kv.x; o[u].y = qv.y & kv.y;
            o[u].z = qv.z & kv.z; o[u].w = qv.w & kv.w;
        }
        for (int q = wid; q < 8; q += 4) {
            int db = q >> 1, ks2 = q & 1;
            const ushort_t* g = A + (size_t)(d0 + db * 32 + row32) * 512 + ks2 * 16 + khalf * 8;
            GL2LDS(g, &As[0][q * 512]);
        }
#pragma unroll
        for (int u = 0; u < 2; ++u)
            *reinterpret_cast<uint4*>(&Bs[0][sq[u] * 512 + sL[u] * 8]) = o[u];
    }
    __syncthreads();

    int buf = 0;
    for (int it = 0; it < 16; ++it) {
        uint4 nq[2], nk[2];
        if (it < 15) {
            int k0n = (it + 1) * 32;
#pragma unroll
            for (int u = 0; u < 2; ++u) {
                int kk = k0n + (sq[u] & 1) * 16 + (sL[u] >> 5) * 8;
                nq[u] = *reinterpret_cast<const uint4*>(&qs[(size_t)sm[u] * 512 + kk]);
                nk[u] = *reinterpret_cast<const uint4*>(&kvs[(size_t)stb[u] * 512 + kk]);
            }
            for (int q = wid; q < 8; q += 4) {
                int db = q >> 1, ks2 = q & 1;
                const ushort_t* g = A + (size_t)(d0 + db * 32 + row32) * 512 + k0n + ks2 * 16 + khalf * 8;
                GL2LDS(g, &As[buf ^ 1][q * 512]);
            }
        }

        __builtin_amdgcn_s_setprio(1);
#pragma unroll
        for (int ks = 0; ks < 2; ++ks) {
            bf16x8 afr[2];
#pragma unroll
            for (int i = 0; i < 2; ++i)
                afr[i] = *reinterpret_cast<const bf16x8*>(
                    &As[buf][(((dw >> 5) + i) * 2 + ks) * 512 + lane * 8]);
#pragma unroll
            for (int j = 0; j < 2; ++j) {
                bf16x8 bfr = *reinterpret_cast<const bf16x8*>(
                    &Bs[buf][(((mw >> 5) + j) * 2 + ks) * 512 + lane * 8]);
#pragma unroll
                for (int i = 0; i < 2; ++i)
                    acc[i][j] = __builtin_amdgcn_mfma_f32_32x32x16_bf16(afr[i], bfr, acc[i][j], 0, 0, 0);
            }
        }
        __builtin_amdgcn_s_setprio(0);

        if (it < 15) {
#pragma unroll
            for (int u = 0; u < 2; ++u) {
                uint4 o;
                o.x = nq[u].x & nk[u].x; o.y = nq[u].y & nk[u].y;
                o.z = nq[u].z & nk[u].z; o.w = nq[u].w & nk[u].w;
                *reinterpret_cast<uint4*>(&Bs[buf ^ 1][sq[u] * 512 + sL[u] * 8]) = o;
            }
        }
        __syncthreads();      // drains vmcnt(0): A(t+1) landed; lgkm: Bs visible
        buf ^= 1;
    }

#pragma unroll
    for (int j = 0; j < 2; ++j) {
        int m = m0 + mw + j * 32 + row32;     // n contiguous across lanes
        int tb = m / N_;
        int n  = m - tb * N_;
        size_t mbase = (size_t)tb * (C_ * N_) + n;
#pragma unroll
        for (int i = 0; i < 2; ++i) {
            int dbase = d0 + dw + i * 32 + 4 * khalf;
            f32x16 a = acc[i][j];
#pragma unroll
            for (int g = 0; g < 4; ++g) {
#pragma unroll
                for (int t = 0; t < 4; ++t) {
                    int d = dbase + t + 8 * g;
                    float val = fmaf(a[4 * g + t], scale[d], shift[d]);
                    size_t ad = mbase + (size_t)d * N_;
                    out[ad] = val + xid[ad];
                }
            }
        }
    }
}

// ---------------------------------------------------------------------------
extern "C" void kernel_launch(void* const* d_in, const int* in_sizes, int n_in,
                              void* d_out, int out_size, void* d_ws, size_t ws_size,
                              hipStream_t stream)
{
    const float* x    = (const float*)d_in[0];
    const float* q_w  = (const float*)d_in[1];
    const float* k_w  = (const float*)d_in[2];
    const float* v_w  = (const float*)d_in[3];
    const float* o_w  = (const float*)d_in[4];
    const float* o_b  = (const float*)d_in[5];
    const float* qg = (const float*)d_in[6],  *qb = (const float*)d_in[7],
               *qm = (const float*)d_in[8],  *qv = (const float*)d_in[9];
    const float* kg = (const float*)d_in[10], *kb = (const float*)d_in[11],
               *km = (const float*)d_in[12], *kv = (const float*)d_in[13];
    const float* vg = (const float*)d_in[14], *vb = (const float*)d_in[15],
               *vm = (const float*)d_in[16], *vv = (const float*)d_in[17];
    const float* og = (const float*)d_in[18], *ob = (const float*)d_in[19],
               *om = (const float*)d_in[20], *ov = (const float*)d_in[21];

    float* out1  = (float*)d_out;
    float* out2f = out1 + OUT1_;

    // d_ws layout
    ushort_t* spk    = (ushort_t*)d_ws;                      // [3][M][512] bf16 spikes
    ushort_t* xs     = spk + (size_t)3 * M_ * 512;           // [M][512] bf16 (m' order)
    ushort_t* wsplit = xs + (size_t)M_ * 512;                // 1536*2*512
    ushort_t* osplit = wsplit + (size_t)1536 * 2 * 512;      // 512*512
    float*    kvpart = (float*)(osplit + (size_t)512 * 512); // [TB][C]
    ushort_t* kvs    = (ushort_t*)(kvpart + TB_ * C_);       // [TB][C]
    float*    scq    = (float*)(kvs + TB_ * C_);
    float*    shq    = scq + 3 * C_;
    float*    sco    = shq + 3 * C_;
    float*    sho    = sco + C_;

    ushort_t* qsp = spk;
    ushort_t* ksp = spk + (size_t)M_ * 512;
    ushort_t* vsp = spk + (size_t)2 * M_ * 512;

    prep_lifx_kernel<<<4096, 256, 0, stream>>>(
        q_w, k_w, v_w, o_w,
        qg, qb, qm, qv, kg, kb, km, kv, vg, vb, vm, vv, og, ob, om, ov, o_b,
        wsplit, osplit, scq, shq, sco, sho, kvpart, x, xs);

    qkv_gemm_lif<<<1200, 512, 0, stream>>>(wsplit, xs, scq, shq, spk, out2f);

    kv_part_kernel<<<256, 256, 0, stream>>>(ksp, vsp, kvpart);

    kv_lif_kernel<<<64, 256, 0, stream>>>(kvpart, kvs);

    out_gemm<<<800, 256, 0, stream>>>(osplit, qsp, kvs, sco, sho, x, out1);
}